// Round 3
// baseline (579.491 us; speedup 1.0000x reference)
//
#include <hip/hip_runtime.h>
#include <hip/hip_bf16.h>
#include <cstdint>
#include <cstddef>

// Problem constants (fixed by the reference):
#define HD   1024            // hidden H
#define NK   4               // heads K
#define DD   512             // H/2
#define LSEQ 2048            // L
#define NB   16              // B
#define MTOT (NB*LSEQ)       // 32768 tokens
#define N1   (HD*NK)         // 4096 projection width

typedef __attribute__((ext_vector_type(4))) float f32x4;
typedef __attribute__((ext_vector_type(8))) short bf16x8;

// async global->LDS, 16B per lane; LDS dest is wave-uniform base + lane*16
#define GLOAD16(gp, lp) __builtin_amdgcn_global_load_lds( \
    (const __attribute__((address_space(1))) void*)(gp),  \
    (__attribute__((address_space(3))) void*)(lp), 16, 0, 0)

static __device__ __forceinline__ ushort f2bf(float f) {
  union { float f; unsigned u; } x; x.f = f;
  unsigned r = x.u + 0x7FFFu + ((x.u >> 16) & 1u);   // RNE
  return (ushort)(r >> 16);
}

// ---------------------------------------------------------------------------
__global__ void detect_mask_kernel(const unsigned char* __restrict__ m, int nbytes,
                                   int* __restrict__ flag) {
  int found = 0;
  for (int i = blockIdx.x * blockDim.x + threadIdx.x; i < nbytes;
       i += gridDim.x * blockDim.x)
    if ((i & 3) && m[i]) found = 1;
  if (__any(found) && (threadIdx.x & 63) == 0) atomicOr(flag, 1);
}

// ---------------------------------------------------------------------------
__global__ void cvt_f32_bf16_kernel(const float* __restrict__ src,
                                    ushort* __restrict__ dst, long n) {
  long stride = (long)gridDim.x * blockDim.x * 4;
  for (long i = ((long)blockIdx.x * blockDim.x + threadIdx.x) * 4; i < n; i += stride) {
    f32x4 v = *(const f32x4*)(src + i);
    ushort4 o; o.x = f2bf(v.x); o.y = f2bf(v.y); o.z = f2bf(v.z); o.w = f2bf(v.w);
    *(ushort4*)(dst + i) = o;
  }
}

// dst[c][r] = bf16(src[r][c]); grid.z = batch
__global__ void transpose_cvt_kernel(const float* __restrict__ src,
                                     ushort* __restrict__ dst,
                                     int R, int C, long sBatch, long dBatch) {
  __shared__ float tile[32][33];
  const float* s = src + blockIdx.z * sBatch;
  ushort* d = dst + blockIdx.z * dBatch;
  int c0 = blockIdx.x * 32, r0 = blockIdx.y * 32;
  int tx = threadIdx.x, ty = threadIdx.y;  // (32, 8)
  #pragma unroll
  for (int i = 0; i < 32; i += 8)
    tile[ty + i][tx] = s[(long)(r0 + ty + i) * C + (c0 + tx)];
  __syncthreads();
  #pragma unroll
  for (int i = 0; i < 32; i += 8)
    d[(long)(c0 + ty + i) * R + (r0 + tx)] = f2bf(tile[tx][ty + i]);
}

// ---------------------------------------------------------------------------
// 256x256 tile, fat-phase schedule: one phase per K-half slot (K=32).
// Phase: {stage 1 slot-pair (4 gload_lds) ; 12 ds_read_b128 ; 32 MFMA ;
//         vmcnt(8) ; barrier}.  4-slot ring per operand: read slot g&3,
// write slot (g+3)&3 (freed 1 barrier ago), prologue stages pairs 0..2.
// 8 waves (2Mx4N), per-wave 128x64 output, LDS 128KB.
// A: [M,lda] bf16 row-major. Bt: [N,ldb] bf16 row-major (pre-transposed).
// MODE 0: Cout[row*ldc+col] = bf16(acc)
// MODE 1: logits[head*MTOT + m0glob+row] += sum_col tanh(acc+b1)*W2
template<int MODE>
__global__ __launch_bounds__(512, 2)
void gemm256_kernel(const ushort* __restrict__ A, int lda,
                    const ushort* __restrict__ Bt, int ldb, int Kdim,
                    ushort* __restrict__ Cout, int ldc,
                    const float* __restrict__ b1, const float* __restrict__ W2,
                    float* __restrict__ logitsOut, int m0glob) {
  // A slots: 4 x 16KB at [0..65536); B slots: 4 x 16KB at [65536..131072)
  __shared__ __align__(16) char lds[131072];

  const int tid = threadIdx.x;
  const int w = tid >> 6, lane = tid & 63;
  const int head = blockIdx.z;

  // XCD-aware swizzle of linear block id (bijective only when nwg%8==0)
  int bid = blockIdx.x + gridDim.x * blockIdx.y;
  const int nwg = gridDim.x * gridDim.y;
  if ((nwg & 7) == 0) {
    const int q = nwg >> 3;
    bid = (bid & 7) * q + (bid >> 3);
  }
  const int nMB = gridDim.x;
  const int m0 = (bid % nMB) * 256;
  const int n0 = (bid / nMB) * 256;

  const ushort* Ap = (MODE == 1) ? (A + head * HD) : A;
  const ushort* Bp = (MODE == 1) ? (Bt + (long)head * DD * HD) : Bt;
  const ushort* Ag = Ap + (long)m0 * lda;
  const ushort* Bg = Bp + (long)n0 * ldb;

  // wave tile: wm in {0,1} -> 128 M-rows; wn in {0..3} -> 64 N-cols
  const int wm = w >> 2, wn = w & 3;
  const int rsel = lane & 15;
  // read-side swizzle: chunk ^= (row>>1)&3 ; lane-constant since frag bases %16==0
  const int chunkC = ((lane >> 4) ^ ((rsel >> 1) & 3)) << 4;
  const int laneA = wm * 8192 + rsel * 64 + chunkC;           // + f*1024, f=0..7
  const int laneB = 65536 + wn * 4096 + rsel * 64 + chunkC;   // + nf*1024

  // staging: thread issues 2 x 16B per STAGE; linear LDS dest,
  // inverse-swizzled global col chunk
  const int stCg = ((lane & 3) ^ ((lane >> 3) & 3)) * 8;      // global col chunk (elems)
  const int stR0 = (w * 2) * 16 + (lane >> 2);                // rows: stR0, stR0+16
  const int stDst0 = (w * 2) * 1024;                          // + j*1024

  // stage K-half h (32 cols at h*32) into slot dsl of region regionByte
  #define STAGE(gbase, ld, regionByte, dsl, h)                                  \
    {                                                                           \
      _Pragma("unroll")                                                         \
      for (int j = 0; j < 2; ++j) {                                             \
        const ushort* gp = (gbase) + (long)(stR0 + j * 16) * (ld) +             \
                           ((h) << 5) + stCg;                                   \
        GLOAD16(gp, lds + (regionByte) + (dsl) * 16384 + stDst0 + j * 1024);    \
      }                                                                         \
    }

  f32x4 acc[8][4] = {};

  // prologue: stage pairs h = 0,1,2 into slots 0,1,2 (12 loads/thread)
  #pragma unroll
  for (int h = 0; h < 3; ++h) {
    STAGE(Ag, lda, 0,     h, h);
    STAGE(Bg, ldb, 65536, h, h);
  }
  asm volatile("s_waitcnt vmcnt(8)" ::: "memory");  // pair 0 landed
  __builtin_amdgcn_sched_barrier(0);
  __builtin_amdgcn_s_barrier();

  const int nph = Kdim >> 5;   // phases of K=32
  for (int g = 0; g < nph; ++g) {
    const int slot = (g & 3) << 14;
    const int dsl = (g + 3) & 3;
    const int h = (g + 3 < nph) ? (g + 3) : (nph - 1);  // clamp; always issue
    STAGE(Ag, lda, 0,     dsl, h);
    STAGE(Bg, ldb, 65536, dsl, h);

    bf16x8 bB[4], aF[8];
    #pragma unroll
    for (int nf = 0; nf < 4; ++nf)
      bB[nf] = *(const bf16x8*)(lds + slot + laneB + nf * 1024);
    #pragma unroll
    for (int f = 0; f < 8; ++f)
      aF[f] = *(const bf16x8*)(lds + slot + laneA + f * 1024);

    __builtin_amdgcn_s_setprio(1);
    #pragma unroll
    for (int f = 0; f < 8; ++f)
      #pragma unroll
      for (int nf = 0; nf < 4; ++nf)
        acc[f][nf] = __builtin_amdgcn_mfma_f32_16x16x32_bf16(
            aF[f], bB[nf], acc[f][nf], 0, 0, 0);
    __builtin_amdgcn_s_setprio(0);

    asm volatile("s_waitcnt vmcnt(8)" ::: "memory");  // pair g+1 landed
    __builtin_amdgcn_sched_barrier(0);
    __builtin_amdgcn_s_barrier();
  }
  asm volatile("s_waitcnt vmcnt(0)" ::: "memory");  // drain DMAs before endpgm

  if constexpr (MODE == 0) {
    #pragma unroll
    for (int mf = 0; mf < 8; ++mf)
      #pragma unroll
      for (int nf = 0; nf < 4; ++nf) {
        const int col = n0 + wn * 64 + nf * 16 + (lane & 15);
        #pragma unroll
        for (int r = 0; r < 4; ++r) {
          const int row = m0 + wm * 128 + mf * 16 + ((lane >> 4) << 2) + r;
          Cout[(long)row * ldc + col] = f2bf(acc[mf][nf][r]);
        }
      }
  } else {
    float b1v[4], w2v[4];
    #pragma unroll
    for (int nf = 0; nf < 4; ++nf) {
      const int col = n0 + wn * 64 + nf * 16 + (lane & 15);
      b1v[nf] = b1[head * DD + col];
      w2v[nf] = W2[head * DD + col];
    }
    #pragma unroll
    for (int mf = 0; mf < 8; ++mf)
      #pragma unroll
      for (int r = 0; r < 4; ++r) {
        float s = 0.f;
        #pragma unroll
        for (int nf = 0; nf < 4; ++nf)
          s += tanhf(acc[mf][nf][r] + b1v[nf]) * w2v[nf];
        s += __shfl_xor(s, 1, 64);
        s += __shfl_xor(s, 2, 64);
        s += __shfl_xor(s, 4, 64);
        s += __shfl_xor(s, 8, 64);
        if ((lane & 15) == 0) {
          const int row = m0glob + m0 + wm * 128 + mf * 16 + ((lane >> 4) << 2) + r;
          atomicAdd(&logitsOut[(long)head * MTOT + row], s);
        }
      }
  }
  #undef STAGE
}

// ---------------------------------------------------------------------------
// masked softmax over L per (k,b) row; out flat [K][B][L] == logits flat layout
__global__ __launch_bounds__(256)
void masked_softmax_kernel(const float* __restrict__ logits,
                           const unsigned char* __restrict__ maskB,
                           const int* __restrict__ maskI,
                           const int* __restrict__ flag,
                           float* __restrict__ out) {
  const int kb = blockIdx.x;          // k*NB + b
  const int b = kb & (NB - 1);
  const long base = (long)kb * LSEQ;
  const bool isByte = (*flag != 0);
  const int tid = threadIdx.x;

  float x[8];
  float mx = -3.0e38f;
  #pragma unroll
  for (int j = 0; j < 8; ++j) {
    int l = tid + j * 256;
    bool msk = isByte ? (maskB[b * LSEQ + l] != 0) : (maskI[b * LSEQ + l] != 0);
    float v = msk ? -1e9f : logits[base + l];
    x[j] = v; mx = fmaxf(mx, v);
  }
  __shared__ float redm[4], reds[4];
  #pragma unroll
  for (int off = 32; off >= 1; off >>= 1) mx = fmaxf(mx, __shfl_xor(mx, off, 64));
  if ((tid & 63) == 0) redm[tid >> 6] = mx;
  __syncthreads();
  mx = fmaxf(fmaxf(redm[0], redm[1]), fmaxf(redm[2], redm[3]));

  float sum = 0.f;
  #pragma unroll
  for (int j = 0; j < 8; ++j) { x[j] = __expf(x[j] - mx); sum += x[j]; }
  #pragma unroll
  for (int off = 32; off >= 1; off >>= 1) sum += __shfl_xor(sum, off, 64);
  if ((tid & 63) == 0) reds[tid >> 6] = sum;
  __syncthreads();
  sum = reds[0] + reds[1] + reds[2] + reds[3];

  float inv = 1.0f / sum;
  #pragma unroll
  for (int j = 0; j < 8; ++j) out[base + tid + j * 256] = x[j] * inv;
}

// ---------------------------------------------------------------------------
extern "C" void kernel_launch(void* const* d_in, const int* in_sizes, int n_in,
                              void* d_out, int out_size, void* d_ws, size_t ws_size,
                              hipStream_t stream) {
  const float* hidden = (const float*)d_in[0];
  const void*  masks  = d_in[1];
  const float* Wp     = (const float*)d_in[2];
  const float* W1     = (const float*)d_in[3];
  const float* b1     = (const float*)d_in[4];
  const float* W2     = (const float*)d_in[5];
  float* out = (float*)d_out;

  // workspace layout (bytes)
  char* ws = (char*)d_ws;
  ushort* WpT      = (ushort*)(ws + 0);                 //  8,388,608  [4096][1024] bf16
  ushort* W1T      = (ushort*)(ws + 8388608);           //  4,194,304  [4][512][1024] bf16
  float*  logits   = (float*) (ws + 12582912);          //    524,288  [4][32768] f32
  int*    flag     = (int*)   (ws + 13107200);          //        256
  ushort* hiddenBf = (ushort*)(ws + 13107456);          // 67,108,864  [32768][1024] bf16
  char*   projBase = ws + 80216320;                     // chunkM*4096 bf16

  size_t fixedBytes = 80216320;
  size_t avail = (ws_size > fixedBytes) ? (ws_size - fixedBytes) : 0;
  long chunkM = (long)(avail / ((long)N1 * 2)) & ~255L;
  if (chunkM > MTOT) chunkM = MTOT;
  if (chunkM < 256) chunkM = 256;  // requires ws_size >= ~82 MB
  ushort* proj = (ushort*)projBase;

  // zero logits + flag (single contiguous region)
  hipMemsetAsync(ws + 12582912, 0, 524288 + 256, stream);

  detect_mask_kernel<<<8, 256, 0, stream>>>((const unsigned char*)masks, NB * LSEQ, flag);
  cvt_f32_bf16_kernel<<<2048, 256, 0, stream>>>(hidden, hiddenBf, (long)MTOT * HD);
  dim3 tb(32, 8);
  transpose_cvt_kernel<<<dim3(N1 / 32, HD / 32, 1), tb, 0, stream>>>(
      Wp, WpT, HD, N1, 0, 0);
  transpose_cvt_kernel<<<dim3(DD / 32, HD / 32, NK), tb, 0, stream>>>(
      W1, W1T, HD, DD, (long)HD * DD, (long)DD * HD);

  for (long m0 = 0; m0 < MTOT; m0 += chunkM) {
    long cm = chunkM; if (m0 + cm > MTOT) cm = MTOT - m0;
    // GEMM1: proj[cm,4096] = hidden[m0:m0+cm] @ Wp   (bf16 out)
    gemm256_kernel<0><<<dim3(cm / 256, N1 / 256, 1), 512, 0, stream>>>(
        hiddenBf + m0 * HD, HD, WpT, HD, HD, proj, N1,
        nullptr, nullptr, nullptr, 0);
    // GEMM2 (+tanh+W2 dot): logits[k, m0:m0+cm] += ...
    gemm256_kernel<1><<<dim3(cm / 256, DD / 256, NK), 512, 0, stream>>>(
        proj, N1, W1T, HD, HD, nullptr, 0,
        b1, W2, logits, (int)m0);
  }

  masked_softmax_kernel<<<NK * NB, 256, 0, stream>>>(
      logits, (const unsigned char*)masks, (const int*)masks, flag, out);
}

// Round 4
// 257.852 us; speedup vs baseline: 2.2474x; 2.2474x over previous
//
#include <hip/hip_runtime.h>
#include <hip/hip_bf16.h>
#include <cstdint>
#include <cstddef>

// Problem constants (fixed by the reference):
#define HD   1024            // hidden H
#define NK   4               // heads K
#define DD   512             // H/2
#define LSEQ 2048            // L
#define NB   16              // B
#define MTOT (NB*LSEQ)       // 32768 tokens
#define NF2  (NK*DD)         // 2048 fused width (4 heads x 512)

typedef __attribute__((ext_vector_type(4))) float f32x4;
typedef __attribute__((ext_vector_type(8))) short bf16x8;

// async global->LDS, 16B per lane; LDS dest is wave-uniform base + lane*16
#define GLOAD16(gp, lp) __builtin_amdgcn_global_load_lds( \
    (const __attribute__((address_space(1))) void*)(gp),  \
    (__attribute__((address_space(3))) void*)(lp), 16, 0, 0)

static __device__ __forceinline__ ushort f2bf(float f) {
  union { float f; unsigned u; } x; x.f = f;
  unsigned r = x.u + 0x7FFFu + ((x.u >> 16) & 1u);   // RNE
  return (ushort)(r >> 16);
}

static __device__ __forceinline__ float fast_tanh(float x) {
  x = fminf(fmaxf(x, -15.f), 15.f);
  float t = __expf(2.0f * x);
  return (t - 1.0f) / (t + 1.0f);
}

// ---------------------------------------------------------------------------
__global__ void detect_mask_kernel(const unsigned char* __restrict__ m, int nbytes,
                                   int* __restrict__ flag) {
  int found = 0;
  for (int i = blockIdx.x * blockDim.x + threadIdx.x; i < nbytes;
       i += gridDim.x * blockDim.x)
    if ((i & 3) && m[i]) found = 1;
  if (__any(found) && (threadIdx.x & 63) == 0) atomicOr(flag, 1);
}

// ---------------------------------------------------------------------------
__global__ void cvt_f32_bf16_kernel(const float* __restrict__ src,
                                    ushort* __restrict__ dst, long n) {
  long stride = (long)gridDim.x * blockDim.x * 4;
  for (long i = ((long)blockIdx.x * blockDim.x + threadIdx.x) * 4; i < n; i += stride) {
    f32x4 v = *(const f32x4*)(src + i);
    ushort4 o; o.x = f2bf(v.x); o.y = f2bf(v.y); o.z = f2bf(v.z); o.w = f2bf(v.w);
    *(ushort4*)(dst + i) = o;
  }
}

// WpH[h][c][j] = bf16(Wp[c][h*1024 + j]);  4M elements, 4 per thread
__global__ void cvt_wp_heads_kernel(const float* __restrict__ Wp,
                                    ushort* __restrict__ WpH) {
  long i4 = ((long)blockIdx.x * blockDim.x + threadIdx.x) * 4;  // < 4*1024*1024
  int h = (int)(i4 >> 20);
  int c = (int)((i4 >> 10) & 1023);
  int j = (int)(i4 & 1023);
  f32x4 v = *(const f32x4*)(Wp + (long)c * (NK * HD) + h * HD + j);
  ushort4 o; o.x = f2bf(v.x); o.y = f2bf(v.y); o.z = f2bf(v.z); o.w = f2bf(v.w);
  *(ushort4*)(WpH + i4) = o;
}

// dst[c][r] = bf16(src[r][c]); grid.z = batch
__global__ void transpose_cvt_kernel(const float* __restrict__ src,
                                     ushort* __restrict__ dst,
                                     int R, int C, long sBatch, long dBatch) {
  __shared__ float tile[32][33];
  const float* s = src + blockIdx.z * sBatch;
  ushort* d = dst + blockIdx.z * dBatch;
  int c0 = blockIdx.x * 32, r0 = blockIdx.y * 32;
  int tx = threadIdx.x, ty = threadIdx.y;  // (32, 8)
  #pragma unroll
  for (int i = 0; i < 32; i += 8)
    tile[ty + i][tx] = s[(long)(r0 + ty + i) * C + (c0 + tx)];
  __syncthreads();
  #pragma unroll
  for (int i = 0; i < 32; i += 8)
    d[(long)(c0 + ty + i) * R + (r0 + tx)] = f2bf(tile[tx][ty + i]);
}

// ---------------------------------------------------------------------------
// 256x256 tile, K-step 32 per phase, register-double-buffered fragments:
// phase g: {stage pair g+3 ; ds_read frags(slot g+1) ; lgkmcnt(12) ;
//           32 MFMA on frags(slot g) ; vmcnt(4) ; barrier}.
// 4-slot LDS ring per operand (16KB slots). 8 waves (2Mx4N), wave = 128x64 out.
// A: [M,lda] bf16 row-major (+z*aZs). Bt: [N,ldb] bf16 row-major (+z*bZs).
// MODE 0: Cout[z*cZs + row*ldc + col] = bf16(acc)
// MODE 1: logits[(col>>9)*MTOT + m0glob+row] += sum_col tanh(acc+b1[col])*W2[col]
template<int MODE>
__global__ __launch_bounds__(512, 2)
void gemm256_kernel(const ushort* __restrict__ A, int lda, long aZs,
                    const ushort* __restrict__ Bt, int ldb, long bZs, int Kdim,
                    ushort* __restrict__ Cout, int ldc, long cZs,
                    const float* __restrict__ b1, const float* __restrict__ W2,
                    float* __restrict__ logitsOut, int m0glob) {
  // A slots: 4 x 16KB at [0..65536); B slots: 4 x 16KB at [65536..131072)
  __shared__ __align__(16) char lds[131072];

  const int tid = threadIdx.x;
  const int w = tid >> 6, lane = tid & 63;
  const int z = blockIdx.z;

  // XCD-aware swizzle of linear block id (bijective only when nwg%8==0)
  int bid = blockIdx.x + gridDim.x * blockIdx.y;
  const int nwg = gridDim.x * gridDim.y;
  if ((nwg & 7) == 0) {
    const int q = nwg >> 3;
    bid = (bid & 7) * q + (bid >> 3);
  }
  const int nMB = gridDim.x;
  const int m0 = (bid % nMB) * 256;
  const int n0 = (bid / nMB) * 256;

  const ushort* Ag = A + z * aZs + (long)m0 * lda;
  const ushort* Bg = Bt + z * bZs + (long)n0 * ldb;

  // wave tile: wm in {0,1} -> 128 M-rows; wn in {0..3} -> 64 N-cols
  const int wm = w >> 2, wn = w & 3;
  const int rsel = lane & 15;
  // read-side swizzle: chunk ^= (row>>1)&3 ; lane-constant since frag bases %16==0
  const int chunkC = ((lane >> 4) ^ ((rsel >> 1) & 3)) << 4;
  const int laneA = wm * 8192 + rsel * 64 + chunkC;           // + f*1024, f=0..7
  const int laneB = 65536 + wn * 4096 + rsel * 64 + chunkC;   // + nf*1024

  // staging: thread issues 2 x 16B per STAGE; linear LDS dest,
  // inverse-swizzled global col chunk
  const int stCg = ((lane & 3) ^ ((lane >> 3) & 3)) * 8;      // global col chunk (elems)
  const int stR0 = (w * 2) * 16 + (lane >> 2);                // rows: stR0, stR0+16
  const int stDst0 = (w * 2) * 1024;                          // + j*1024

  // stage K-half h (32 cols at h*32) into slot dsl of region regionByte
  #define STAGE(gbase, ld, regionByte, dsl, h)                                  \
    {                                                                           \
      _Pragma("unroll")                                                         \
      for (int j = 0; j < 2; ++j) {                                             \
        const ushort* gp = (gbase) + (long)(stR0 + j * 16) * (ld) +             \
                           ((h) << 5) + stCg;                                   \
        GLOAD16(gp, lds + (regionByte) + (dsl) * 16384 + stDst0 + j * 1024);    \
      }                                                                         \
    }

  f32x4 acc[8][4] = {};
  const int nph = Kdim >> 5;   // phases of K=32

  // prologue: stage pairs 0,1,2 into slots 0,1,2
  #pragma unroll
  for (int h = 0; h < 3; ++h) {
    STAGE(Ag, lda, 0,     h, h);
    STAGE(Bg, ldb, 65536, h, h);
  }
  asm volatile("s_waitcnt vmcnt(4)" ::: "memory");  // pairs 0,1 landed
  __builtin_amdgcn_sched_barrier(0);
  __builtin_amdgcn_s_barrier();

  bf16x8 aCur[8], bCur[4], aNxt[8], bNxt[4];
  #pragma unroll
  for (int nf = 0; nf < 4; ++nf) bCur[nf] = *(const bf16x8*)(lds + laneB + nf * 1024);
  #pragma unroll
  for (int f = 0; f < 8; ++f)    aCur[f] = *(const bf16x8*)(lds + laneA + f * 1024);

  // phase g: MFMA on CA/CB (slot g, regs); prefetch NA/NB_ from slot g+1;
  // stage pair g+3 into slot (g+3)&3 (freed by barrier at end of phase g-1).
  #define PHASE(g, CA, CB, NA, NB_)                                             \
    {                                                                           \
      const int dsl = ((g) + 3) & 3;                                            \
      const int hh = ((g) + 3 < nph) ? (g) + 3 : nph - 1;                       \
      STAGE(Ag, lda, 0,     dsl, hh);                                           \
      STAGE(Bg, ldb, 65536, dsl, hh);                                           \
      const int rs = (((g) + 1) & 3) << 14;                                     \
      _Pragma("unroll")                                                         \
      for (int nf = 0; nf < 4; ++nf)                                            \
        NB_[nf] = *(const bf16x8*)(lds + rs + laneB + nf * 1024);               \
      _Pragma("unroll")                                                         \
      for (int f = 0; f < 8; ++f)                                               \
        NA[f] = *(const bf16x8*)(lds + rs + laneA + f * 1024);                  \
      asm volatile("s_waitcnt lgkmcnt(12)" ::: "memory");                       \
      __builtin_amdgcn_sched_barrier(0);                                        \
      __builtin_amdgcn_s_setprio(1);                                            \
      _Pragma("unroll")                                                         \
      for (int f = 0; f < 8; ++f)                                               \
        _Pragma("unroll")                                                       \
        for (int nf = 0; nf < 4; ++nf)                                          \
          acc[f][nf] = __builtin_amdgcn_mfma_f32_16x16x32_bf16(                 \
              CA[f], CB[nf], acc[f][nf], 0, 0, 0);                              \
      __builtin_amdgcn_s_setprio(0);                                            \
      asm volatile("s_waitcnt vmcnt(4)" ::: "memory");                          \
      __builtin_amdgcn_sched_barrier(0);                                        \
      __builtin_amdgcn_s_barrier();                                             \
    }

  for (int g = 0; g < nph; g += 2) {
    PHASE(g,     aCur, bCur, aNxt, bNxt);
    PHASE(g + 1, aNxt, bNxt, aCur, bCur);
  }
  asm volatile("s_waitcnt vmcnt(0)" ::: "memory");  // drain DMAs before endpgm

  if constexpr (MODE == 0) {
    #pragma unroll
    for (int mf = 0; mf < 8; ++mf)
      #pragma unroll
      for (int nf = 0; nf < 4; ++nf) {
        const int col = n0 + wn * 64 + nf * 16 + (lane & 15);
        #pragma unroll
        for (int r = 0; r < 4; ++r) {
          const int row = m0 + wm * 128 + mf * 16 + ((lane >> 4) << 2) + r;
          Cout[z * cZs + (long)row * ldc + col] = f2bf(acc[mf][nf][r]);
        }
      }
  } else {
    float b1v[4], w2v[4];
    #pragma unroll
    for (int nf = 0; nf < 4; ++nf) {
      const int col = n0 + wn * 64 + nf * 16 + (lane & 15);
      b1v[nf] = b1[col];
      w2v[nf] = W2[col];
    }
    const long headBase = (long)((n0 + wn * 64) >> 9) * MTOT + m0glob;
    #pragma unroll
    for (int mf = 0; mf < 8; ++mf)
      #pragma unroll
      for (int r = 0; r < 4; ++r) {
        float s = 0.f;
        #pragma unroll
        for (int nf = 0; nf < 4; ++nf)
          s += fast_tanh(acc[mf][nf][r] + b1v[nf]) * w2v[nf];
        s += __shfl_xor(s, 1, 64);
        s += __shfl_xor(s, 2, 64);
        s += __shfl_xor(s, 4, 64);
        s += __shfl_xor(s, 8, 64);
        if ((lane & 15) == 0) {
          const int row = m0 + wm * 128 + mf * 16 + ((lane >> 4) << 2) + r;
          atomicAdd(&logitsOut[headBase + row], s);
        }
      }
  }
  #undef PHASE
  #undef STAGE
}

// ---------------------------------------------------------------------------
// masked softmax over L per (k,b) row; out flat [K][B][L] == logits flat layout
__global__ __launch_bounds__(256)
void masked_softmax_kernel(const float* __restrict__ logits,
                           const unsigned char* __restrict__ maskB,
                           const int* __restrict__ maskI,
                           const int* __restrict__ flag,
                           float* __restrict__ out) {
  const int kb = blockIdx.x;          // k*NB + b
  const int b = kb & (NB - 1);
  const long base = (long)kb * LSEQ;
  const bool isByte = (*flag != 0);
  const int tid = threadIdx.x;

  float x[8];
  float mx = -3.0e38f;
  #pragma unroll
  for (int j = 0; j < 8; ++j) {
    int l = tid + j * 256;
    bool msk = isByte ? (maskB[b * LSEQ + l] != 0) : (maskI[b * LSEQ + l] != 0);
    float v = msk ? -1e9f : logits[base + l];
    x[j] = v; mx = fmaxf(mx, v);
  }
  __shared__ float redm[4], reds[4];
  #pragma unroll
  for (int off = 32; off >= 1; off >>= 1) mx = fmaxf(mx, __shfl_xor(mx, off, 64));
  if ((tid & 63) == 0) redm[tid >> 6] = mx;
  __syncthreads();
  mx = fmaxf(fmaxf(redm[0], redm[1]), fmaxf(redm[2], redm[3]));

  float sum = 0.f;
  #pragma unroll
  for (int j = 0; j < 8; ++j) { x[j] = __expf(x[j] - mx); sum += x[j]; }
  #pragma unroll
  for (int off = 32; off >= 1; off >>= 1) sum += __shfl_xor(sum, off, 64);
  if ((tid & 63) == 0) reds[tid >> 6] = sum;
  __syncthreads();
  sum = reds[0] + reds[1] + reds[2] + reds[3];

  float inv = 1.0f / sum;
  #pragma unroll
  for (int j = 0; j < 8; ++j) out[base + tid + j * 256] = x[j] * inv;
}

// ---------------------------------------------------------------------------
extern "C" void kernel_launch(void* const* d_in, const int* in_sizes, int n_in,
                              void* d_out, int out_size, void* d_ws, size_t ws_size,
                              hipStream_t stream) {
  const float* hidden = (const float*)d_in[0];
  const void*  masks  = d_in[1];
  const float* Wp     = (const float*)d_in[2];
  const float* W1     = (const float*)d_in[3];
  const float* b1     = (const float*)d_in[4];
  const float* W2     = (const float*)d_in[5];
  float* out = (float*)d_out;

  // workspace layout (bytes)
  char* ws = (char*)d_ws;
  ushort* W1T      = (ushort*)(ws + 0);                 //  4,194,304  [4][512][1024] bf16
  ushort* WpH      = (ushort*)(ws + 4194304);           //  8,388,608  [4][1024][1024] bf16
  ushort* WfT      = (ushort*)(ws + 12582912);          //  4,194,304  [2048][1024] bf16
  float*  logits   = (float*) (ws + 16777216);          //    524,288  [4][32768] f32
  int*    flag     = (int*)   (ws + 17301504);          //        256
  ushort* hiddenBf = (ushort*)(ws + 17301760);          // chunkM*2048 bytes

  const size_t fixedBytes = 17301760;
  size_t avail = (ws_size > fixedBytes) ? (ws_size - fixedBytes) : 0;
  long chunkM = (long)(avail / ((long)HD * 2)) & ~255L;
  if (chunkM > MTOT) chunkM = MTOT;
  if (chunkM < 256) chunkM = 256;  // requires ws_size >= ~17.8 MB

  // zero logits + flag (single contiguous region)
  hipMemsetAsync(ws + 16777216, 0, 524288 + 256, stream);

  detect_mask_kernel<<<8, 256, 0, stream>>>((const unsigned char*)masks, NB * LSEQ, flag);

  // W1T[h][d][j] = bf16(W1[h][j][d])
  dim3 tb(32, 8);
  transpose_cvt_kernel<<<dim3(DD / 32, HD / 32, NK), tb, 0, stream>>>(
      W1, W1T, HD, DD, (long)HD * DD, (long)DD * HD);
  // WpH[h][c][j] = bf16(Wp[c][h*1024+j])
  cvt_wp_heads_kernel<<<4096, 256, 0, stream>>>(Wp, WpH);

  // WfT[h*512+d][c] = sum_j W1T[h][d][j] * WpH[h][c][j]   (= (Wp@W1)^T per head)
  gemm256_kernel<0><<<dim3(2, 4, 4), 512, 0, stream>>>(
      W1T, HD, (long)DD * HD,
      WpH, HD, (long)HD * HD, HD,
      WfT, HD, (long)DD * HD,
      nullptr, nullptr, nullptr, 0);

  for (long m0 = 0; m0 < MTOT; m0 += chunkM) {
    long cm = chunkM; if (m0 + cm > MTOT) cm = MTOT - m0;
    cvt_f32_bf16_kernel<<<2048, 256, 0, stream>>>(
        hidden + m0 * HD, hiddenBf, cm * HD);
    // logits[(col>>9)][m0+row] += sum_col tanh(hidden@WfT^T + b1)*W2
    gemm256_kernel<1><<<dim3(cm / 256, NF2 / 256, 1), 512, 0, stream>>>(
        hiddenBf, HD, 0,
        WfT, HD, 0, HD,
        nullptr, 0, 0,
        b1, W2, logits, (int)m0);
  }

  masked_softmax_kernel<<<NK * NB, 256, 0, stream>>>(
      logits, (const unsigned char*)masks, (const int*)masks, flag, out);
}

// Round 5
// 246.838 us; speedup vs baseline: 2.3477x; 1.0446x over previous
//
#include <hip/hip_runtime.h>
#include <hip/hip_bf16.h>
#include <cstdint>
#include <cstddef>

// Problem constants (fixed by the reference):
#define HD   1024            // hidden H
#define NK   4               // heads K
#define DD   512             // H/2
#define LSEQ 2048            // L
#define NB   16              // B
#define MTOT (NB*LSEQ)       // 32768 tokens
#define NF2  (NK*DD)         // 2048 fused width (4 heads x 512)

typedef __attribute__((ext_vector_type(4))) float f32x4;
typedef __attribute__((ext_vector_type(8))) short bf16x8;

// async global->LDS, 16B per lane; LDS dest is wave-uniform base + lane*16
#define GLOAD16(gp, lp) __builtin_amdgcn_global_load_lds( \
    (const __attribute__((address_space(1))) void*)(gp),  \
    (__attribute__((address_space(3))) void*)(lp), 16, 0, 0)

static __device__ __forceinline__ ushort f2bf(float f) {
  union { float f; unsigned u; } x; x.f = f;
  unsigned r = x.u + 0x7FFFu + ((x.u >> 16) & 1u);   // RNE
  return (ushort)(r >> 16);
}

static __device__ __forceinline__ float fast_tanh(float x) {
  x = fminf(fmaxf(x, -15.f), 15.f);
  float t = __expf(2.0f * x);
  return (t - 1.0f) / (t + 1.0f);
}

// ---------------------------------------------------------------------------
__global__ void detect_mask_kernel(const unsigned char* __restrict__ m, int nbytes,
                                   int* __restrict__ flag) {
  int found = 0;
  for (int i = blockIdx.x * blockDim.x + threadIdx.x; i < nbytes;
       i += gridDim.x * blockDim.x)
    if ((i & 3) && m[i]) found = 1;
  if (__any(found) && (threadIdx.x & 63) == 0) atomicOr(flag, 1);
}

// ---------------------------------------------------------------------------
__global__ void cvt_f32_bf16_kernel(const float* __restrict__ src,
                                    ushort* __restrict__ dst, long n) {
  long stride = (long)gridDim.x * blockDim.x * 4;
  for (long i = ((long)blockIdx.x * blockDim.x + threadIdx.x) * 4; i < n; i += stride) {
    f32x4 v = *(const f32x4*)(src + i);
    ushort4 o; o.x = f2bf(v.x); o.y = f2bf(v.y); o.z = f2bf(v.z); o.w = f2bf(v.w);
    *(ushort4*)(dst + i) = o;
  }
}

// WpH[h][c][j] = bf16(Wp[c][h*1024 + j]);  4M elements, 4 per thread
__global__ void cvt_wp_heads_kernel(const float* __restrict__ Wp,
                                    ushort* __restrict__ WpH) {
  long i4 = ((long)blockIdx.x * blockDim.x + threadIdx.x) * 4;  // < 4*1024*1024
  int h = (int)(i4 >> 20);
  int c = (int)((i4 >> 10) & 1023);
  int j = (int)(i4 & 1023);
  f32x4 v = *(const f32x4*)(Wp + (long)c * (NK * HD) + h * HD + j);
  ushort4 o; o.x = f2bf(v.x); o.y = f2bf(v.y); o.z = f2bf(v.z); o.w = f2bf(v.w);
  *(ushort4*)(WpH + i4) = o;
}

// dst[c][r] = bf16(src[r][c]); grid.z = batch
__global__ void transpose_cvt_kernel(const float* __restrict__ src,
                                     ushort* __restrict__ dst,
                                     int R, int C, long sBatch, long dBatch) {
  __shared__ float tile[32][33];
  const float* s = src + blockIdx.z * sBatch;
  ushort* d = dst + blockIdx.z * dBatch;
  int c0 = blockIdx.x * 32, r0 = blockIdx.y * 32;
  int tx = threadIdx.x, ty = threadIdx.y;  // (32, 8)
  #pragma unroll
  for (int i = 0; i < 32; i += 8)
    tile[ty + i][tx] = s[(long)(r0 + ty + i) * C + (c0 + tx)];
  __syncthreads();
  #pragma unroll
  for (int i = 0; i < 32; i += 8)
    d[(long)(c0 + ty + i) * R + (r0 + tx)] = f2bf(tile[tx][ty + i]);
}

// ---------------------------------------------------------------------------
// 256x256 tile, BK=64, m201-style 8-phase schedule. 8 waves; wave (r,c):
// r=w>>2 (64-row band), c=w&3 (32-col band). Quadrant (mh,nh) = 128x128 of C;
// per phase: one quadrant x K=64 = 16 MFMA/wave. Phase order [00,01,11,10].
// LDS: A = 2buf x 2half x [128 rows][64 cols] (16KB each) at 0..64K; B same
// at 64K..128K. XOR-swizzle: chunk ^= (row&7); staged via inverse-permuted
// global source, linear LDS dest. Stage order per 4-phase block [A0,B0,B1,A1];
// vmcnt(4) at phase tails except p2/p6.
// A: [M,lda] bf16 row-major (+z*aZs). Bt: [N,ldb] bf16 row-major (+z*bZs).
// MODE 0: Cout[z*cZs + row*ldc + col] = bf16(acc)
// MODE 1: logits[(n0>>9)*MTOT + m0glob+row] += sum_col tanh(acc+b1[col])*W2[col]
template<int MODE>
__global__ __launch_bounds__(512, 2)
void gemm256_kernel(const ushort* __restrict__ A, int lda, long aZs,
                    const ushort* __restrict__ Bt, int ldb, long bZs, int Kdim,
                    ushort* __restrict__ Cout, int ldc, long cZs,
                    const float* __restrict__ b1, const float* __restrict__ W2,
                    float* __restrict__ logitsOut, int m0glob) {
  __shared__ __align__(16) char lds[131072];

  const int tid = threadIdx.x;
  const int w = tid >> 6, lane = tid & 63;
  const int z = blockIdx.z;

  // XCD-aware swizzle of linear block id (bijective only when nwg%8==0)
  int bid = blockIdx.x + gridDim.x * blockIdx.y;
  const int nwg = gridDim.x * gridDim.y;
  if ((nwg & 7) == 0) {
    const int q = nwg >> 3;
    bid = (bid & 7) * q + (bid >> 3);
  }
  const int nMB = gridDim.x;
  const int m0 = (bid % nMB) * 256;
  const int n0 = (bid / nMB) * 256;

  const ushort* Ag = A + z * aZs + (long)m0 * lda;
  const ushort* Bg = Bt + z * bZs + (long)n0 * ldb;

  const int r = w >> 2, c = w & 3;
  const int rsel = lane & 15, ch = lane >> 4;

  // read-side swizzled bases (byte offsets); chunk(3b) = ((ks<<2)|ch) ^ (rsel&7)
  const int sw0 = ((ch ^ (rsel & 7)) << 4);
  const int baseA0 = r * 8192 + rsel * 128 + sw0;           // + buf*32768 + mh*16384 + mf*2048
  const int baseA1 = baseA0 ^ 64;                           // ks=1
  const int baseB0 = 65536 + c * 4096 + rsel * 128 + sw0;   // + buf*32768 + nh*16384 + nf*2048
  const int baseB1 = baseB0 ^ 64;

  // staging: 2 x 16B per thread per half-tile; linear LDS dest,
  // inverse-swizzled global col chunk
  const int stRow = lane >> 3;                       // 0..7
  const int stCol = ((lane & 7) ^ (lane >> 3)) * 8;  // global col chunk (elems)

  // stage half-tile HALF of K-tile KT into buf SBUF of region REG (0=A, 65536=B)
  #define STG(REG, GP, LD, SBUF, SHALF, SKT)                                    \
    {                                                                           \
      _Pragma("unroll")                                                         \
      for (int jj = 0; jj < 2; ++jj) {                                          \
        const ushort* gsrc = (GP) +                                             \
            (long)((SHALF) * 128 + w * 16 + jj * 8 + stRow) * (LD) +            \
            (SKT) * 64 + stCol;                                                 \
        GLOAD16(gsrc, lds + (REG) + (SBUF) * 32768 + (SHALF) * 16384 +          \
                (w * 2 + jj) * 1024);                                           \
      }                                                                         \
    }

  f32x4 acc[8][4] = {};    // acc[mh*4+mf][nh*2+nf]
  bf16x8 aF[4][2], bB[2][2][2];

  #define PHASE(BUF, MH, NH, LA, LB, SREG, SGP, SLD, SBUF, SHALF, SKT, VM)      \
    {                                                                           \
      if (LA) {                                                                 \
        _Pragma("unroll")                                                       \
        for (int mf = 0; mf < 4; ++mf) {                                        \
          aF[mf][0] = *(const bf16x8*)(lds + (BUF) * 32768 + (MH) * 16384 +     \
                                       mf * 2048 + baseA0);                     \
          aF[mf][1] = *(const bf16x8*)(lds + (BUF) * 32768 + (MH) * 16384 +     \
                                       mf * 2048 + baseA1);                     \
        }                                                                       \
      }                                                                         \
      if (LB) {                                                                 \
        _Pragma("unroll")                                                       \
        for (int nf = 0; nf < 2; ++nf) {                                        \
          bB[NH][nf][0] = *(const bf16x8*)(lds + (BUF) * 32768 + (NH) * 16384 + \
                                           nf * 2048 + baseB0);                 \
          bB[NH][nf][1] = *(const bf16x8*)(lds + (BUF) * 32768 + (NH) * 16384 + \
                                           nf * 2048 + baseB1);                 \
        }                                                                       \
      }                                                                         \
      STG(SREG, SGP, SLD, SBUF, SHALF, SKT);                                    \
      __builtin_amdgcn_s_barrier();                                             \
      asm volatile("s_waitcnt lgkmcnt(0)" ::: "memory");                        \
      __builtin_amdgcn_sched_barrier(0);                                        \
      __builtin_amdgcn_s_setprio(1);                                            \
      _Pragma("unroll")                                                         \
      for (int ks = 0; ks < 2; ++ks)                                            \
        _Pragma("unroll")                                                       \
        for (int mf = 0; mf < 4; ++mf)                                          \
          _Pragma("unroll")                                                     \
          for (int nf = 0; nf < 2; ++nf)                                        \
            acc[(MH)*4+mf][(NH)*2+nf] =                                         \
                __builtin_amdgcn_mfma_f32_16x16x32_bf16(                        \
                    aF[mf][ks], bB[NH][nf][ks], acc[(MH)*4+mf][(NH)*2+nf],      \
                    0, 0, 0);                                                   \
      __builtin_amdgcn_s_setprio(0);                                            \
      if (VM) {                                                                 \
        asm volatile("s_waitcnt vmcnt(4)" ::: "memory");                        \
        __builtin_amdgcn_sched_barrier(0);                                      \
      }                                                                         \
      __builtin_amdgcn_s_barrier();                                             \
    }

  const int ntk = Kdim >> 6;    // K-tiles of 64
  const int nt2 = Kdim >> 7;    // 8-phase iterations (2 K-tiles each)

  // prologue: stage buf0 <- kt 0, order [A0, B0, B1, A1]
  STG(0,     Ag, lda, 0, 0, 0);
  STG(65536, Bg, ldb, 0, 0, 0);
  STG(65536, Bg, ldb, 0, 1, 0);
  STG(0,     Ag, lda, 0, 1, 0);
  asm volatile("s_waitcnt vmcnt(4)" ::: "memory");  // A0,B0 landed
  __builtin_amdgcn_sched_barrier(0);
  __builtin_amdgcn_s_barrier();

  for (int j = 0; j < nt2; ++j) {
    const int k1 = 2 * j + 1;
    const int k2 = (2 * j + 2 < ntk) ? (2 * j + 2) : (ntk - 1);  // clamp, always issue
    // phases 0-3: compute buf0 (kt 2j), stage buf1 <- k1
    PHASE(0, 0, 0, 1, 1, 0,     Ag, lda, 1, 0, k1, 1)
    PHASE(0, 0, 1, 0, 1, 65536, Bg, ldb, 1, 0, k1, 1)
    PHASE(0, 1, 1, 1, 0, 65536, Bg, ldb, 1, 1, k1, 0)
    PHASE(0, 1, 0, 0, 0, 0,     Ag, lda, 1, 1, k1, 1)
    // phases 4-7: compute buf1 (kt 2j+1), stage buf0 <- k2
    PHASE(1, 0, 0, 1, 1, 0,     Ag, lda, 0, 0, k2, 1)
    PHASE(1, 0, 1, 0, 1, 65536, Bg, ldb, 0, 0, k2, 1)
    PHASE(1, 1, 1, 1, 0, 65536, Bg, ldb, 0, 1, k2, 0)
    PHASE(1, 1, 0, 0, 0, 0,     Ag, lda, 0, 1, k2, 1)
  }
  asm volatile("s_waitcnt vmcnt(0)" ::: "memory");  // drain DMAs

  // C coverage: row(am) = m0 + (am>>2)*128 + r*64 + (am&3)*16 + (lane>>4)*4 + rr
  //             col(an) = n0 + (an>>1)*128 + c*32 + (an&1)*16 + (lane&15)
  if constexpr (MODE == 0) {
    #pragma unroll
    for (int am = 0; am < 8; ++am)
      #pragma unroll
      for (int an = 0; an < 4; ++an) {
        const int col = n0 + (an >> 1) * 128 + c * 32 + (an & 1) * 16 + (lane & 15);
        #pragma unroll
        for (int rr = 0; rr < 4; ++rr) {
          const int row = m0 + (am >> 2) * 128 + r * 64 + (am & 3) * 16 +
                          ((lane >> 4) << 2) + rr;
          Cout[z * cZs + (long)row * ldc + col] = f2bf(acc[am][an][rr]);
        }
      }
  } else {
    float b1v[4], w2v[4];
    #pragma unroll
    for (int an = 0; an < 4; ++an) {
      const int col = n0 + (an >> 1) * 128 + c * 32 + (an & 1) * 16 + (lane & 15);
      b1v[an] = b1[col];
      w2v[an] = W2[col];
    }
    const long headBase = (long)(n0 >> 9) * MTOT + m0glob + m0;
    #pragma unroll
    for (int am = 0; am < 8; ++am)
      #pragma unroll
      for (int rr = 0; rr < 4; ++rr) {
        float s = 0.f;
        #pragma unroll
        for (int an = 0; an < 4; ++an)
          s += fast_tanh(acc[am][an][rr] + b1v[an]) * w2v[an];
        s += __shfl_xor(s, 1, 64);
        s += __shfl_xor(s, 2, 64);
        s += __shfl_xor(s, 4, 64);
        s += __shfl_xor(s, 8, 64);
        if ((lane & 15) == 0) {
          const int row = (am >> 2) * 128 + r * 64 + (am & 3) * 16 +
                          ((lane >> 4) << 2) + rr;
          atomicAdd(&logitsOut[headBase + row], s);
        }
      }
  }
  #undef PHASE
  #undef STG
}

// ---------------------------------------------------------------------------
// masked softmax over L per (k,b) row; out flat [K][B][L] == logits flat layout
__global__ __launch_bounds__(256)
void masked_softmax_kernel(const float* __restrict__ logits,
                           const unsigned char* __restrict__ maskB,
                           const int* __restrict__ maskI,
                           const int* __restrict__ flag,
                           float* __restrict__ out) {
  const int kb = blockIdx.x;          // k*NB + b
  const int b = kb & (NB - 1);
  const long base = (long)kb * LSEQ;
  const bool isByte = (*flag != 0);
  const int tid = threadIdx.x;

  float x[8];
  float mx = -3.0e38f;
  #pragma unroll
  for (int j = 0; j < 8; ++j) {
    int l = tid + j * 256;
    bool msk = isByte ? (maskB[b * LSEQ + l] != 0) : (maskI[b * LSEQ + l] != 0);
    float v = msk ? -1e9f : logits[base + l];
    x[j] = v; mx = fmaxf(mx, v);
  }
  __shared__ float redm[4], reds[4];
  #pragma unroll
  for (int off = 32; off >= 1; off >>= 1) mx = fmaxf(mx, __shfl_xor(mx, off, 64));
  if ((tid & 63) == 0) redm[tid >> 6] = mx;
  __syncthreads();
  mx = fmaxf(fmaxf(redm[0], redm[1]), fmaxf(redm[2], redm[3]));

  float sum = 0.f;
  #pragma unroll
  for (int j = 0; j < 8; ++j) { x[j] = __expf(x[j] - mx); sum += x[j]; }
  #pragma unroll
  for (int off = 32; off >= 1; off >>= 1) sum += __shfl_xor(sum, off, 64);
  if ((tid & 63) == 0) reds[tid >> 6] = sum;
  __syncthreads();
  sum = reds[0] + reds[1] + reds[2] + reds[3];

  float inv = 1.0f / sum;
  #pragma unroll
  for (int j = 0; j < 8; ++j) out[base + tid + j * 256] = x[j] * inv;
}

// ---------------------------------------------------------------------------
extern "C" void kernel_launch(void* const* d_in, const int* in_sizes, int n_in,
                              void* d_out, int out_size, void* d_ws, size_t ws_size,
                              hipStream_t stream) {
  const float* hidden = (const float*)d_in[0];
  const void*  masks  = d_in[1];
  const float* Wp     = (const float*)d_in[2];
  const float* W1     = (const float*)d_in[3];
  const float* b1     = (const float*)d_in[4];
  const float* W2     = (const float*)d_in[5];
  float* out = (float*)d_out;

  // workspace layout (bytes)
  char* ws = (char*)d_ws;
  ushort* W1T      = (ushort*)(ws + 0);                 //  4,194,304  [4][512][1024] bf16
  ushort* WpH      = (ushort*)(ws + 4194304);           //  8,388,608  [4][1024][1024] bf16
  ushort* WfT      = (ushort*)(ws + 12582912);          //  4,194,304  [2048][1024] bf16
  float*  logits   = (float*) (ws + 16777216);          //    524,288  [4][32768] f32
  int*    flag     = (int*)   (ws + 17301504);          //        256
  ushort* hiddenBf = (ushort*)(ws + 17301760);          // chunkM*2048 bytes

  const size_t fixedBytes = 17301760;
  size_t avail = (ws_size > fixedBytes) ? (ws_size - fixedBytes) : 0;
  long chunkM = (long)(avail / ((long)HD * 2)) & ~255L;
  if (chunkM > MTOT) chunkM = MTOT;
  if (chunkM < 256) chunkM = 256;  // requires ws_size >= ~17.8 MB

  // zero logits + flag (single contiguous region)
  hipMemsetAsync(ws + 16777216, 0, 524288 + 256, stream);

  detect_mask_kernel<<<8, 256, 0, stream>>>((const unsigned char*)masks, NB * LSEQ, flag);

  // W1T[h][d][j] = bf16(W1[h][j][d])
  dim3 tb(32, 8);
  transpose_cvt_kernel<<<dim3(DD / 32, HD / 32, NK), tb, 0, stream>>>(
      W1, W1T, HD, DD, (long)HD * DD, (long)DD * HD);
  // WpH[h][c][j] = bf16(Wp[c][h*1024+j])
  cvt_wp_heads_kernel<<<4096, 256, 0, stream>>>(Wp, WpH);

  // WfT[h*512+d][c] = sum_j W1T[h][d][j] * WpH[h][c][j]   (= (Wp@W1)^T per head)
  gemm256_kernel<0><<<dim3(2, 4, 4), 512, 0, stream>>>(
      W1T, HD, (long)DD * HD,
      WpH, HD, (long)HD * HD, HD,
      WfT, HD, (long)DD * HD,
      nullptr, nullptr, nullptr, 0);

  for (long m0 = 0; m0 < MTOT; m0 += chunkM) {
    long cm = chunkM; if (m0 + cm > MTOT) cm = MTOT - m0;
    cvt_f32_bf16_kernel<<<2048, 256, 0, stream>>>(
        hidden + m0 * HD, hiddenBf, cm * HD);
    // logits[head][m0+row] += sum_col tanh(hidden@WfT^T + b1)*W2
    gemm256_kernel<1><<<dim3(cm / 256, NF2 / 256, 1), 512, 0, stream>>>(
        hiddenBf, HD, 0,
        WfT, HD, 0, HD,
        nullptr, 0, 0,
        b1, W2, logits, (int)m0);
  }

  masked_softmax_kernel<<<NK * NB, 256, 0, stream>>>(
      logits, (const unsigned char*)masks, (const int*)masks, flag, out);
}

// Round 6
// 246.746 us; speedup vs baseline: 2.3485x; 1.0004x over previous
//
#include <hip/hip_runtime.h>
#include <hip/hip_bf16.h>
#include <cstdint>
#include <cstddef>

// Problem constants (fixed by the reference):
#define HD   1024            // hidden H
#define NK   4               // heads K
#define DD   512             // H/2
#define LSEQ 2048            // L
#define NB   16              // B
#define MTOT (NB*LSEQ)       // 32768 tokens
#define NF2  (NK*DD)         // 2048 fused width (4 heads x 512)

typedef __attribute__((ext_vector_type(4))) float f32x4;
typedef __attribute__((ext_vector_type(8))) short bf16x8;

// async global->LDS, 16B per lane; LDS dest is wave-uniform base + lane*16
#define GLOAD16(gp, lp) __builtin_amdgcn_global_load_lds( \
    (const __attribute__((address_space(1))) void*)(gp),  \
    (__attribute__((address_space(3))) void*)(lp), 16, 0, 0)

static __device__ __forceinline__ ushort f2bf(float f) {
  union { float f; unsigned u; } x; x.f = f;
  unsigned r = x.u + 0x7FFFu + ((x.u >> 16) & 1u);   // RNE
  return (ushort)(r >> 16);
}

static __device__ __forceinline__ float fast_tanh(float x) {
  x = fminf(fmaxf(x, -15.f), 15.f);
  float t = __expf(2.0f * x);
  return (t - 1.0f) / (t + 1.0f);
}

// ---------------------------------------------------------------------------
__global__ void detect_mask_kernel(const unsigned char* __restrict__ m, int nbytes,
                                   int* __restrict__ flag) {
  int found = 0;
  for (int i = blockIdx.x * blockDim.x + threadIdx.x; i < nbytes;
       i += gridDim.x * blockDim.x)
    if ((i & 3) && m[i]) found = 1;
  if (__any(found) && (threadIdx.x & 63) == 0) atomicOr(flag, 1);
}

// ---------------------------------------------------------------------------
__global__ void cvt_f32_bf16_kernel(const float* __restrict__ src,
                                    ushort* __restrict__ dst, long n) {
  long stride = (long)gridDim.x * blockDim.x * 4;
  for (long i = ((long)blockIdx.x * blockDim.x + threadIdx.x) * 4; i < n; i += stride) {
    f32x4 v = *(const f32x4*)(src + i);
    ushort4 o; o.x = f2bf(v.x); o.y = f2bf(v.y); o.z = f2bf(v.z); o.w = f2bf(v.w);
    *(ushort4*)(dst + i) = o;
  }
}

// WpH[h][c][j] = bf16(Wp[c][h*1024 + j]);  4M elements, 4 per thread
__global__ void cvt_wp_heads_kernel(const float* __restrict__ Wp,
                                    ushort* __restrict__ WpH) {
  long i4 = ((long)blockIdx.x * blockDim.x + threadIdx.x) * 4;  // < 4*1024*1024
  int h = (int)(i4 >> 20);
  int c = (int)((i4 >> 10) & 1023);
  int j = (int)(i4 & 1023);
  f32x4 v = *(const f32x4*)(Wp + (long)c * (NK * HD) + h * HD + j);
  ushort4 o; o.x = f2bf(v.x); o.y = f2bf(v.y); o.z = f2bf(v.z); o.w = f2bf(v.w);
  *(ushort4*)(WpH + i4) = o;
}

// dst[c][r] = bf16(src[r][c]); grid.z = batch
__global__ void transpose_cvt_kernel(const float* __restrict__ src,
                                     ushort* __restrict__ dst,
                                     int R, int C, long sBatch, long dBatch) {
  __shared__ float tile[32][33];
  const float* s = src + blockIdx.z * sBatch;
  ushort* d = dst + blockIdx.z * dBatch;
  int c0 = blockIdx.x * 32, r0 = blockIdx.y * 32;
  int tx = threadIdx.x, ty = threadIdx.y;  // (32, 8)
  #pragma unroll
  for (int i = 0; i < 32; i += 8)
    tile[ty + i][tx] = s[(long)(r0 + ty + i) * C + (c0 + tx)];
  __syncthreads();
  #pragma unroll
  for (int i = 0; i < 32; i += 8)
    d[(long)(c0 + ty + i) * R + (r0 + tx)] = f2bf(tile[tx][ty + i]);
}

// ---------------------------------------------------------------------------
// 256x256 tile, BK=64, 8-phase schedule with COMPILER-MANAGED lgkm waits
// (no explicit lgkmcnt pinning — hipcc emits fine-grained lgkmcnt(N) per
// dependent MFMA, overlapping DS drain with MFMA issue; m141 lesson).
// 8 waves; wave (r,c): r=w>>2 (64-row band), c=w&3 (32-col band).
// Quadrant (mh,nh) = 128x128 of C; per phase: one quadrant x K=64 = 16 MFMA.
// Phase order [00,01,11,10]. LDS: A = 2buf x 2half x 16KB at 0..64K; B same
// at 64K..128K. XOR-swizzle chunk ^= (row&7) on reads; inverse-permuted
// global source, linear LDS dest. Stage order per 4-phase block [A0,B0,B1,A1];
// vmcnt(4) at phase tails except p2/p6.
// A: [M,lda] bf16 row-major (+z*aZs). Bt: [N,ldb] bf16 row-major (+z*bZs).
// MODE 0: Cout[z*cZs + row*ldc + col] = bf16(acc)
// MODE 1: logits[(n0>>9)*MTOT + m0glob+row] += sum_col tanh(acc+b1[col])*W2[col]
template<int MODE>
__global__ __launch_bounds__(512, 2)
void gemm256_kernel(const ushort* __restrict__ A, int lda, long aZs,
                    const ushort* __restrict__ Bt, int ldb, long bZs, int Kdim,
                    ushort* __restrict__ Cout, int ldc, long cZs,
                    const float* __restrict__ b1, const float* __restrict__ W2,
                    float* __restrict__ logitsOut, int m0glob) {
  __shared__ __align__(16) char lds[131072];

  const int tid = threadIdx.x;
  const int w = tid >> 6, lane = tid & 63;
  const int z = blockIdx.z;

  // XCD-aware swizzle of linear block id (bijective only when nwg%8==0)
  int bid = blockIdx.x + gridDim.x * blockIdx.y;
  const int nwg = gridDim.x * gridDim.y;
  if ((nwg & 7) == 0) {
    const int q = nwg >> 3;
    bid = (bid & 7) * q + (bid >> 3);
  }
  const int nMB = gridDim.x;
  const int m0 = (bid % nMB) * 256;
  const int n0 = (bid / nMB) * 256;

  const ushort* Ag = A + z * aZs + (long)m0 * lda;
  const ushort* Bg = Bt + z * bZs + (long)n0 * ldb;

  const int r = w >> 2, c = w & 3;
  const int rsel = lane & 15, ch = lane >> 4;

  // read-side swizzled bases (byte offsets); chunk(3b) = ((ks<<2)|ch) ^ (rsel&7)
  const int sw0 = ((ch ^ (rsel & 7)) << 4);
  const int baseA0 = r * 8192 + rsel * 128 + sw0;           // + buf*32768 + mh*16384 + mf*2048
  const int baseA1 = baseA0 ^ 64;                           // ks=1
  const int baseB0 = 65536 + c * 4096 + rsel * 128 + sw0;   // + buf*32768 + nh*16384 + nf*2048
  const int baseB1 = baseB0 ^ 64;

  // staging: 2 x 16B per thread per half-tile; linear LDS dest,
  // inverse-swizzled global col chunk
  const int stRow = lane >> 3;                       // 0..7
  const int stCol = ((lane & 7) ^ (lane >> 3)) * 8;  // global col chunk (elems)

  // stage half-tile HALF of K-tile KT into buf SBUF of region REG (0=A, 65536=B)
  #define STG(REG, GP, LD, SBUF, SHALF, SKT)                                    \
    {                                                                           \
      _Pragma("unroll")                                                         \
      for (int jj = 0; jj < 2; ++jj) {                                          \
        const ushort* gsrc = (GP) +                                             \
            (long)((SHALF) * 128 + w * 16 + jj * 8 + stRow) * (LD) +            \
            (SKT) * 64 + stCol;                                                 \
        GLOAD16(gsrc, lds + (REG) + (SBUF) * 32768 + (SHALF) * 16384 +          \
                (w * 2 + jj) * 1024);                                           \
      }                                                                         \
    }

  f32x4 acc[8][4] = {};    // acc[mh*4+mf][nh*2+nf]
  bf16x8 aF[4][2], bB[2][2][2];

  #define PHASE(BUF, MH, NH, LA, LB, SREG, SGP, SLD, SBUF, SHALF, SKT, VM)      \
    {                                                                           \
      if (LA) {                                                                 \
        _Pragma("unroll")                                                       \
        for (int mf = 0; mf < 4; ++mf) {                                        \
          aF[mf][0] = *(const bf16x8*)(lds + (BUF) * 32768 + (MH) * 16384 +     \
                                       mf * 2048 + baseA0);                     \
          aF[mf][1] = *(const bf16x8*)(lds + (BUF) * 32768 + (MH) * 16384 +     \
                                       mf * 2048 + baseA1);                     \
        }                                                                       \
      }                                                                         \
      if (LB) {                                                                 \
        _Pragma("unroll")                                                       \
        for (int nf = 0; nf < 2; ++nf) {                                        \
          bB[NH][nf][0] = *(const bf16x8*)(lds + (BUF) * 32768 + (NH) * 16384 + \
                                           nf * 2048 + baseB0);                 \
          bB[NH][nf][1] = *(const bf16x8*)(lds + (BUF) * 32768 + (NH) * 16384 + \
                                           nf * 2048 + baseB1);                 \
        }                                                                       \
      }                                                                         \
      STG(SREG, SGP, SLD, SBUF, SHALF, SKT);                                    \
      __builtin_amdgcn_s_barrier();                                             \
      __builtin_amdgcn_s_setprio(1);                                            \
      _Pragma("unroll")                                                         \
      for (int ks = 0; ks < 2; ++ks)                                            \
        _Pragma("unroll")                                                       \
        for (int mf = 0; mf < 4; ++mf)                                          \
          _Pragma("unroll")                                                     \
          for (int nf = 0; nf < 2; ++nf)                                        \
            acc[(MH)*4+mf][(NH)*2+nf] =                                         \
                __builtin_amdgcn_mfma_f32_16x16x32_bf16(                        \
                    aF[mf][ks], bB[NH][nf][ks], acc[(MH)*4+mf][(NH)*2+nf],      \
                    0, 0, 0);                                                   \
      __builtin_amdgcn_s_setprio(0);                                            \
      if (VM) {                                                                 \
        asm volatile("s_waitcnt vmcnt(4)" ::: "memory");                        \
        __builtin_amdgcn_sched_barrier(0);                                      \
      }                                                                         \
      __builtin_amdgcn_s_barrier();                                             \
    }

  const int ntk = Kdim >> 6;    // K-tiles of 64
  const int nt2 = Kdim >> 7;    // 8-phase iterations (2 K-tiles each)

  // prologue: stage buf0 <- kt 0, order [A0, B0, B1, A1]
  STG(0,     Ag, lda, 0, 0, 0);
  STG(65536, Bg, ldb, 0, 0, 0);
  STG(65536, Bg, ldb, 0, 1, 0);
  STG(0,     Ag, lda, 0, 1, 0);
  asm volatile("s_waitcnt vmcnt(4)" ::: "memory");  // A0,B0 landed
  __builtin_amdgcn_sched_barrier(0);
  __builtin_amdgcn_s_barrier();

  for (int j = 0; j < nt2; ++j) {
    const int k1 = 2 * j + 1;
    const int k2 = (2 * j + 2 < ntk) ? (2 * j + 2) : (ntk - 1);  // clamp, always issue
    // phases 0-3: compute buf0 (kt 2j), stage buf1 <- k1
    PHASE(0, 0, 0, 1, 1, 0,     Ag, lda, 1, 0, k1, 1)
    PHASE(0, 0, 1, 0, 1, 65536, Bg, ldb, 1, 0, k1, 1)
    PHASE(0, 1, 1, 1, 0, 65536, Bg, ldb, 1, 1, k1, 0)
    PHASE(0, 1, 0, 0, 0, 0,     Ag, lda, 1, 1, k1, 1)
    // phases 4-7: compute buf1 (kt 2j+1), stage buf0 <- k2
    PHASE(1, 0, 0, 1, 1, 0,     Ag, lda, 0, 0, k2, 1)
    PHASE(1, 0, 1, 0, 1, 65536, Bg, ldb, 0, 0, k2, 1)
    PHASE(1, 1, 1, 1, 0, 65536, Bg, ldb, 0, 1, k2, 0)
    PHASE(1, 1, 0, 0, 0, 0,     Ag, lda, 0, 1, k2, 1)
  }
  asm volatile("s_waitcnt vmcnt(0)" ::: "memory");  // drain DMAs

  // C coverage: row(am) = m0 + (am>>2)*128 + r*64 + (am&3)*16 + (lane>>4)*4 + rr
  //             col(an) = n0 + (an>>1)*128 + c*32 + (an&1)*16 + (lane&15)
  if constexpr (MODE == 0) {
    #pragma unroll
    for (int am = 0; am < 8; ++am)
      #pragma unroll
      for (int an = 0; an < 4; ++an) {
        const int col = n0 + (an >> 1) * 128 + c * 32 + (an & 1) * 16 + (lane & 15);
        #pragma unroll
        for (int rr = 0; rr < 4; ++rr) {
          const int row = m0 + (am >> 2) * 128 + r * 64 + (am & 3) * 16 +
                          ((lane >> 4) << 2) + rr;
          Cout[z * cZs + (long)row * ldc + col] = f2bf(acc[am][an][rr]);
        }
      }
  } else {
    float b1v[4], w2v[4];
    #pragma unroll
    for (int an = 0; an < 4; ++an) {
      const int col = n0 + (an >> 1) * 128 + c * 32 + (an & 1) * 16 + (lane & 15);
      b1v[an] = b1[col];
      w2v[an] = W2[col];
    }
    const long headBase = (long)(n0 >> 9) * MTOT + m0glob + m0;
    #pragma unroll
    for (int am = 0; am < 8; ++am)
      #pragma unroll
      for (int rr = 0; rr < 4; ++rr) {
        float s = 0.f;
        #pragma unroll
        for (int an = 0; an < 4; ++an)
          s += fast_tanh(acc[am][an][rr] + b1v[an]) * w2v[an];
        s += __shfl_xor(s, 1, 64);
        s += __shfl_xor(s, 2, 64);
        s += __shfl_xor(s, 4, 64);
        s += __shfl_xor(s, 8, 64);
        if ((lane & 15) == 0) {
          const int row = (am >> 2) * 128 + r * 64 + (am & 3) * 16 +
                          ((lane >> 4) << 2) + rr;
          atomicAdd(&logitsOut[headBase + row], s);
        }
      }
  }
  #undef PHASE
  #undef STG
}

// ---------------------------------------------------------------------------
// masked softmax over L per (k,b) row; out flat [K][B][L] == logits flat layout
__global__ __launch_bounds__(256)
void masked_softmax_kernel(const float* __restrict__ logits,
                           const unsigned char* __restrict__ maskB,
                           const int* __restrict__ maskI,
                           const int* __restrict__ flag,
                           float* __restrict__ out) {
  const int kb = blockIdx.x;          // k*NB + b
  const int b = kb & (NB - 1);
  const long base = (long)kb * LSEQ;
  const bool isByte = (*flag != 0);
  const int tid = threadIdx.x;

  float x[8];
  float mx = -3.0e38f;
  #pragma unroll
  for (int j = 0; j < 8; ++j) {
    int l = tid + j * 256;
    bool msk = isByte ? (maskB[b * LSEQ + l] != 0) : (maskI[b * LSEQ + l] != 0);
    float v = msk ? -1e9f : logits[base + l];
    x[j] = v; mx = fmaxf(mx, v);
  }
  __shared__ float redm[4], reds[4];
  #pragma unroll
  for (int off = 32; off >= 1; off >>= 1) mx = fmaxf(mx, __shfl_xor(mx, off, 64));
  if ((tid & 63) == 0) redm[tid >> 6] = mx;
  __syncthreads();
  mx = fmaxf(fmaxf(redm[0], redm[1]), fmaxf(redm[2], redm[3]));

  float sum = 0.f;
  #pragma unroll
  for (int j = 0; j < 8; ++j) { x[j] = __expf(x[j] - mx); sum += x[j]; }
  #pragma unroll
  for (int off = 32; off >= 1; off >>= 1) sum += __shfl_xor(sum, off, 64);
  if ((tid & 63) == 0) reds[tid >> 6] = sum;
  __syncthreads();
  sum = reds[0] + reds[1] + reds[2] + reds[3];

  float inv = 1.0f / sum;
  #pragma unroll
  for (int j = 0; j < 8; ++j) out[base + tid + j * 256] = x[j] * inv;
}

// ---------------------------------------------------------------------------
extern "C" void kernel_launch(void* const* d_in, const int* in_sizes, int n_in,
                              void* d_out, int out_size, void* d_ws, size_t ws_size,
                              hipStream_t stream) {
  const float* hidden = (const float*)d_in[0];
  const void*  masks  = d_in[1];
  const float* Wp     = (const float*)d_in[2];
  const float* W1     = (const float*)d_in[3];
  const float* b1     = (const float*)d_in[4];
  const float* W2     = (const float*)d_in[5];
  float* out = (float*)d_out;

  // workspace layout (bytes)
  char* ws = (char*)d_ws;
  ushort* W1T      = (ushort*)(ws + 0);                 //  4,194,304  [4][512][1024] bf16
  ushort* WpH      = (ushort*)(ws + 4194304);           //  8,388,608  [4][1024][1024] bf16
  ushort* WfT      = (ushort*)(ws + 12582912);          //  4,194,304  [2048][1024] bf16
  float*  logits   = (float*) (ws + 16777216);          //    524,288  [4][32768] f32
  int*    flag     = (int*)   (ws + 17301504);          //        256
  ushort* hiddenBf = (ushort*)(ws + 17301760);          // chunkM*2048 bytes

  const size_t fixedBytes = 17301760;
  size_t avail = (ws_size > fixedBytes) ? (ws_size - fixedBytes) : 0;
  long chunkM = (long)(avail / ((long)HD * 2)) & ~255L;
  if (chunkM > MTOT) chunkM = MTOT;
  if (chunkM < 256) chunkM = 256;  // requires ws_size >= ~17.8 MB

  // zero logits + flag (single contiguous region)
  hipMemsetAsync(ws + 16777216, 0, 524288 + 256, stream);

  detect_mask_kernel<<<8, 256, 0, stream>>>((const unsigned char*)masks, NB * LSEQ, flag);

  // W1T[h][d][j] = bf16(W1[h][j][d])
  dim3 tb(32, 8);
  transpose_cvt_kernel<<<dim3(DD / 32, HD / 32, NK), tb, 0, stream>>>(
      W1, W1T, HD, DD, (long)HD * DD, (long)DD * HD);
  // WpH[h][c][j] = bf16(Wp[c][h*1024+j])
  cvt_wp_heads_kernel<<<4096, 256, 0, stream>>>(Wp, WpH);

  // WfT[h*512+d][c] = sum_j W1T[h][d][j] * WpH[h][c][j]   (= (Wp@W1)^T per head)
  gemm256_kernel<0><<<dim3(2, 4, 4), 512, 0, stream>>>(
      W1T, HD, (long)DD * HD,
      WpH, HD, (long)HD * HD, HD,
      WfT, HD, (long)DD * HD,
      nullptr, nullptr, nullptr, 0);

  for (long m0 = 0; m0 < MTOT; m0 += chunkM) {
    long cm = chunkM; if (m0 + cm > MTOT) cm = MTOT - m0;
    cvt_f32_bf16_kernel<<<2048, 256, 0, stream>>>(
        hidden + m0 * HD, hiddenBf, cm * HD);
    // logits[head][m0+row] += sum_col tanh(hidden@WfT^T + b1)*W2
    gemm256_kernel<1><<<dim3(cm / 256, NF2 / 256, 1), 512, 0, stream>>>(
        hiddenBf, HD, 0,
        WfT, HD, 0, HD,
        nullptr, 0, 0,
        b1, W2, logits, (int)m0);
  }

  masked_softmax_kernel<<<NK * NB, 256, 0, stream>>>(
      logits, (const unsigned char*)masks, (const int*)masks, flag, out);
}